// Round 1
// baseline (679.030 us; speedup 1.0000x reference)
//
#include <hip/hip_runtime.h>

#define BB 512
#define SS 512
#define TT 78
#define TP 80      // padded tag count (multiple of 4)
#define NT 128     // 2 waves

__device__ __forceinline__ float fexp(float x) { return __expf(x); }
__device__ __forceinline__ float flog(float x) { return __logf(x); }

__global__ __launch_bounds__(NT) void crf_fwd_kernel(
    const float* __restrict__ em,          // [B,S,T]
    const unsigned int* __restrict__ mi32, // [B,S] int32 OR packed bool bytes
    const float* __restrict__ st,          // [T]
    const float* __restrict__ en,          // [T]
    const float* __restrict__ tr,          // [T,T] row j (src), col t (dst)
    float* __restrict__ out)               // [B]
{
    const int b = blockIdx.x;
    const int t = threadIdx.x;

    __shared__ float sE0[TP];   // exp(score - m_sc)
    __shared__ float sE1[TP];   // exp(alpha - m_al)
    __shared__ float sM[2];     // m broadcast (lane-0 state values)
    __shared__ float sred[4];
    __shared__ int sflag;

    // ---- one-time mask layout detection (int32 elements vs 1-byte bools) ----
    if (t == 0) sflag = 1;
    __syncthreads();
    {
        bool okl = true;
        for (int k = t; k < 512; k += NT) okl = okl && (mi32[k] <= 1u);
        if (!okl) atomicAnd(&sflag, 0);
    }
    __syncthreads();
    const bool mask_int = (sflag != 0);
    const unsigned char* mi8 = (const unsigned char*)mi32;

    // ---- preload exp(trans[j][t]) column for my tag t into registers ----
    float et[TP];
    #pragma unroll
    for (int j = 0; j < TT; ++j) {
        float v = (t < TT) ? tr[j * TT + t] : 0.0f;
        et[j] = fexp(v);
    }
    et[TT] = 0.0f; et[TT + 1] = 0.0f;   // j-padding (multiplied by E=0)

    // ---- init state: start + emissions[:,0] ----
    float sc, al;
    {
        float e0 = (t < TT) ? em[(size_t)b * SS * TT + t] : 0.0f;
        float s0 = (t < TT) ? st[t] : 0.0f;
        sc = s0 + e0;
        al = sc;
    }
    if (t == 0) { sM[0] = sc; sM[1] = al; }
    if (t == TT || t == TT + 1) { sE0[t] = 0.0f; sE1[t] = 0.0f; }  // E padding

    // ---- prefetch step 1 ----
    float em_n = (t < TT) ? em[((size_t)b * SS + 1) * TT + t] : 0.0f;
    unsigned int mk_n = mask_int ? mi32[b * SS + 1] : (unsigned int)mi8[b * SS + 1];

    for (int i = 1; i < SS; ++i) {
        __syncthreads();                   // A: sM visible; prev matvec reads done
        const float m_sc = sM[0];
        const float m_al = sM[1];
        if (t < TT) {
            sE0[t] = fexp(sc - m_sc);
            sE1[t] = fexp(al - m_al);
        }
        const float emi = em_n;
        const unsigned int mki = mk_n;
        if (i + 1 < SS) {                  // prefetch next step (hides HBM/L2 latency)
            em_n = (t < TT) ? em[((size_t)b * SS + (i + 1)) * TT + t] : 0.0f;
            mk_n = mask_int ? mi32[b * SS + i + 1] : (unsigned int)mi8[b * SS + i + 1];
        }
        __syncthreads();                   // B: sE visible
        // matvec: v[t] = sum_j E_state[j] * exp(trans[j][t])
        float a0 = 0.f, a1 = 0.f, a2 = 0.f, a3 = 0.f;
        float c0 = 0.f, c1 = 0.f, c2 = 0.f, c3 = 0.f;
        const float4* e0p = (const float4*)sE0;
        const float4* e1p = (const float4*)sE1;
        #pragma unroll
        for (int k = 0; k < TP / 4; ++k) {
            float4 x = e0p[k];
            float4 y = e1p[k];
            a0 = fmaf(x.x, et[4 * k + 0], a0);
            a1 = fmaf(x.y, et[4 * k + 1], a1);
            a2 = fmaf(x.z, et[4 * k + 2], a2);
            a3 = fmaf(x.w, et[4 * k + 3], a3);
            c0 = fmaf(y.x, et[4 * k + 0], c0);
            c1 = fmaf(y.y, et[4 * k + 1], c1);
            c2 = fmaf(y.z, et[4 * k + 2], c2);
            c3 = fmaf(y.w, et[4 * k + 3], c3);
        }
        float v0 = (a0 + a1) + (a2 + a3);
        float v1 = (c0 + c1) + (c2 + c3);
        if (t < TT) {
            float nsc = emi + m_sc + flog(v0);
            float nal = emi + m_al + flog(v1);
            sc = mki ? nsc : sc;   // masked score update
            al = nal;              // partition always updates
        }
        if (t == 0) { sM[0] = sc; sM[1] = al; }
    }

    // ---- final: lse over tags with end transitions ----
    float fsc = (t < TT) ? sc + en[t] : -1e30f;
    float fal = (t < TT) ? al + en[t] : -1e30f;
    float msc = fsc, mal = fal;
    #pragma unroll
    for (int o = 32; o > 0; o >>= 1) {
        msc = fmaxf(msc, __shfl_xor(msc, o));
        mal = fmaxf(mal, __shfl_xor(mal, o));
    }
    __syncthreads();
    if ((t & 63) == 0) { sred[(t >> 6) * 2 + 0] = msc; sred[(t >> 6) * 2 + 1] = mal; }
    __syncthreads();
    msc = fmaxf(sred[0], sred[2]);
    mal = fmaxf(sred[1], sred[3]);
    float es = (t < TT) ? fexp(fsc - msc) : 0.0f;
    float ea = (t < TT) ? fexp(fal - mal) : 0.0f;
    #pragma unroll
    for (int o = 32; o > 0; o >>= 1) {
        es += __shfl_xor(es, o);
        ea += __shfl_xor(ea, o);
    }
    __syncthreads();
    if ((t & 63) == 0) { sred[(t >> 6) * 2 + 0] = es; sred[(t >> 6) * 2 + 1] = ea; }
    __syncthreads();
    if (t == 0) {
        float score_final = msc + flog(sred[0] + sred[2]);
        float partition   = mal + flog(sred[1] + sred[3]);
        out[b] = partition - score_final;
    }
}

extern "C" void kernel_launch(void* const* d_in, const int* in_sizes, int n_in,
                              void* d_out, int out_size, void* d_ws, size_t ws_size,
                              hipStream_t stream) {
    const float* emissions    = (const float*)d_in[0];
    const unsigned int* mask  = (const unsigned int*)d_in[1];
    const float* start_trans  = (const float*)d_in[2];
    const float* end_trans    = (const float*)d_in[3];
    const float* transitions  = (const float*)d_in[4];
    float* out = (float*)d_out;

    crf_fwd_kernel<<<BB, NT, 0, stream>>>(emissions, mask, start_trans,
                                          end_trans, transitions, out);
}

// Round 2
// 353.489 us; speedup vs baseline: 1.9209x; 1.9209x over previous
//
#include <hip/hip_runtime.h>

#define BB 512
#define SS 512
#define TT 78
#define TP 80      // padded tag count (multiple of 4)
#define NT 128     // 2 waves: wave0 = score chain, wave1 = alpha chain

typedef float v2f __attribute__((ext_vector_type(2)));
typedef float v4f __attribute__((ext_vector_type(4)));

__device__ __forceinline__ float fexp(float x) { return __expf(x); }
__device__ __forceinline__ float flog(float x) { return __logf(x); }

__global__ __launch_bounds__(NT) void crf_fwd_kernel(
    const float* __restrict__ em,          // [B,S,T]
    const unsigned int* __restrict__ mi32, // [B,S] int32 OR packed bool bytes
    const float* __restrict__ st,          // [T]
    const float* __restrict__ en_,         // [T]
    const float* __restrict__ tr,          // [T,T] row j (src), col t (dst)
    float* __restrict__ out)               // [B]
{
    const int b    = blockIdx.x;
    const int tid  = threadIdx.x;
    const int wid  = tid >> 6;            // 0 = score (masked), 1 = alpha
    const int lane = tid & 63;
    const bool has2 = lane < (TT - 64);   // lanes 0..13 own a second tag
    const int t0  = lane;                 // always < 78
    const int t1  = lane + 64;
    const int t1c = has2 ? t1 : (TT - 1); // clamped index for safe loads

    __shared__ __align__(16) float sE[2][TP];  // per-wave exp-state vector
    __shared__ float sfin[2];
    __shared__ int sflag;

    // ---- one-time mask layout detection (int32 elements vs 1-byte bools) ----
    if (tid == 0) sflag = 1;
    __syncthreads();
    {
        bool okl = true;
        for (int k = tid; k < 512; k += NT) okl = okl && (mi32[k] <= 1u);
        if (!okl) atomicAnd(&sflag, 0);
    }
    __syncthreads();
    const bool mask_int = (sflag != 0);
    const unsigned char* mi8 = (const unsigned char*)mi32;
    const bool is_alpha = (wid == 1);

    // ---- preload exp(trans[j][t]) columns for my two tags into registers ----
    v2f et0[TP / 2];   // 80 floats: exp(tr[j][t0]), j = 0..79
    v2f et1[TP / 2];   // 80 floats: exp(tr[j][t1c])
    #pragma unroll
    for (int j = 0; j < TT; ++j) {
        ((float*)et0)[j] = fexp(tr[j * TT + t0]);
        ((float*)et1)[j] = fexp(tr[j * TT + t1c]);
    }
    ((float*)et0)[TT] = 0.f; ((float*)et0)[TT + 1] = 0.f;
    ((float*)et1)[TT] = 0.f; ((float*)et1)[TT + 1] = 0.f;

    // ---- init state: start + emissions[:,0] ----
    const size_t base = (size_t)b * SS * TT;
    float sc0 = st[t0] + em[base + t0];
    float sc1 = st[t1c] + em[base + t1c];   // junk for !has2, never used

    // zero the LDS padding entries (written once, never overwritten)
    if (lane == 14 || lane == 15) sE[wid][64 + lane] = 0.f;  // slots 78, 79

    // ---- prefetch step 1 ----
    const float* rp = em + base + TT;
    float en0 = rp[t0];
    float en1 = rp[t1c];
    unsigned int mk_n = mask_int ? mi32[b * SS + 1] : (unsigned int)mi8[b * SS + 1];

    for (int i = 1; i < SS; ++i) {
        // broadcast m = state[0] (lane 0's t0 value) via SALU
        float m = __builtin_amdgcn_readfirstlane(sc0);
        sE[wid][lane] = fexp(sc0 - m);
        if (has2) sE[wid][64 + lane] = fexp(sc1 - m);

        const float emi0 = en0, emi1 = en1;
        const unsigned int mki = mk_n;
        if (i + 1 < SS) {                   // prefetch next step
            rp += TT;
            en0 = rp[t0];
            en1 = rp[t1c];
            mk_n = mask_int ? mi32[b * SS + i + 1] : (unsigned int)mi8[b * SS + i + 1];
        }
        __builtin_amdgcn_wave_barrier();    // keep reads after writes (no HW cost)

        // matvec: v[t] = sum_j E[j] * exp(trans[j][t]); packed fp32 FMAs
        v2f a0 = {0.f, 0.f}, a1 = {0.f, 0.f};   // accumulators for t0
        v2f c0 = {0.f, 0.f}, c1 = {0.f, 0.f};   // accumulators for t1
        const v4f* ep = (const v4f*)sE[wid];
        #pragma unroll
        for (int k = 0; k < TP / 4; ++k) {      // 20 iters, 4 pk-FMA each
            v4f x = ep[k];
            v2f xlo = {x.x, x.y};
            v2f xhi = {x.z, x.w};
            a0 = __builtin_elementwise_fma(xlo, et0[2 * k + 0], a0);
            a1 = __builtin_elementwise_fma(xhi, et0[2 * k + 1], a1);
            c0 = __builtin_elementwise_fma(xlo, et1[2 * k + 0], c0);
            c1 = __builtin_elementwise_fma(xhi, et1[2 * k + 1], c1);
        }
        float v0 = (a0.x + a0.y) + (a1.x + a1.y);
        float v1 = (c0.x + c0.y) + (c1.x + c1.y);

        float nsc0 = emi0 + m + flog(v0);
        float nsc1 = emi1 + m + flog(v1);
        const bool upd = is_alpha | (mki != 0);   // alpha always updates
        sc0 = upd ? nsc0 : sc0;
        sc1 = upd ? nsc1 : sc1;
    }

    // ---- final: lse over tags with end transitions (in-wave reduce) ----
    float f0 = sc0 + en_[t0];
    float f1 = has2 ? (sc1 + en_[t1c]) : -1e30f;
    float mm = fmaxf(f0, f1);
    #pragma unroll
    for (int o = 32; o > 0; o >>= 1) mm = fmaxf(mm, __shfl_xor(mm, o));
    float s = fexp(f0 - mm) + (has2 ? fexp(f1 - mm) : 0.f);
    #pragma unroll
    for (int o = 32; o > 0; o >>= 1) s += __shfl_xor(s, o);
    if (lane == 0) sfin[wid] = mm + flog(s);
    __syncthreads();
    if (tid == 0) out[b] = sfin[1] - sfin[0];   // partition - score_final
}

extern "C" void kernel_launch(void* const* d_in, const int* in_sizes, int n_in,
                              void* d_out, int out_size, void* d_ws, size_t ws_size,
                              hipStream_t stream) {
    const float* emissions    = (const float*)d_in[0];
    const unsigned int* mask  = (const unsigned int*)d_in[1];
    const float* start_trans  = (const float*)d_in[2];
    const float* end_trans    = (const float*)d_in[3];
    const float* transitions  = (const float*)d_in[4];
    float* out = (float*)d_out;

    crf_fwd_kernel<<<BB, NT, 0, stream>>>(emissions, mask, start_trans,
                                          end_trans, transitions, out);
}

// Round 3
// 232.443 us; speedup vs baseline: 2.9213x; 1.5208x over previous
//
#include <hip/hip_runtime.h>

#define BB 512
#define SS 512
#define TT 78
#define TP 80      // padded tag count (multiple of 4)
#define NT 128     // 2 waves: wave0 = score chain, wave1 = alpha chain

typedef float v2f __attribute__((ext_vector_type(2)));
typedef float v4f __attribute__((ext_vector_type(4)));

__device__ __forceinline__ float fexp(float x) { return __expf(x); }
__device__ __forceinline__ float flog(float x) { return __logf(x); }

__global__ __launch_bounds__(NT, 1) void crf_fwd_kernel(
    const float* __restrict__ em,          // [B,S,T]
    const unsigned int* __restrict__ mi32, // [B,S] int32 OR packed bool bytes
    const float* __restrict__ st,          // [T]
    const float* __restrict__ en_,         // [T]
    const float* __restrict__ tr,          // [T,T] row j (src), col t (dst)
    float* __restrict__ out)               // [B]
{
    const int b    = blockIdx.x;
    const int tid  = threadIdx.x;
    const int wid  = tid >> 6;            // 0 = score (masked), 1 = alpha
    const int lane = tid & 63;
    const bool has2 = lane < (TT - 64);   // lanes 0..13 own a second tag
    const int t0  = lane;                 // always < 78
    const int t1  = lane + 64;
    const int t1c = has2 ? t1 : (TT - 1); // clamped index for safe loads

    __shared__ __align__(16) float sE[2][TP];  // per-wave exp-state vector
    __shared__ float sfin[2];
    __shared__ int sflag;

    // ---- one-time mask layout detection (int32 elements vs 1-byte bools) ----
    if (tid == 0) sflag = 1;
    __syncthreads();
    {
        bool okl = true;
        for (int k = tid; k < 512; k += NT) okl = okl && (mi32[k] <= 1u);
        if (!okl) atomicAnd(&sflag, 0);
    }
    __syncthreads();
    const bool mask_int = (sflag != 0);
    const unsigned char* mi8 = (const unsigned char*)mi32;
    const bool is_alpha = (wid == 1);

    // ---- preload exp(trans[j][t]) columns for my two tags into registers ----
    v2f et0[TP / 2];   // 80 floats: exp(tr[j][t0]), j = 0..79
    v2f et1[TP / 2];   // 80 floats: exp(tr[j][t1c])
    #pragma unroll
    for (int j = 0; j < TT; ++j) {
        ((float*)et0)[j] = fexp(tr[j * TT + t0]);
        ((float*)et1)[j] = fexp(tr[j * TT + t1c]);
    }
    ((float*)et0)[TT] = 0.f; ((float*)et0)[TT + 1] = 0.f;
    ((float*)et1)[TT] = 0.f; ((float*)et1)[TT + 1] = 0.f;

    // ---- init state: start + emissions[:,0] ----
    const size_t base = (size_t)b * SS * TT;
    float sc0 = st[t0] + em[base + t0];
    float sc1 = st[t1c] + em[base + t1c];   // junk for !has2, never used

    // zero the LDS padding entries (written once, never overwritten)
    if (lane == 14 || lane == 15) sE[wid][64 + lane] = 0.f;  // slots 78, 79

    // ---- prefetch step 1 ----
    const float* rp = em + base + TT;
    float en0 = rp[t0];
    float en1 = rp[t1c];
    unsigned int mk_n = mask_int ? mi32[b * SS + 1] : (unsigned int)mi8[b * SS + 1];

    for (int i = 1; i < SS; ++i) {
        // broadcast m = state[0] (lane 0's t0 value) via SALU
        float m = __builtin_amdgcn_readfirstlane(sc0);
        sE[wid][lane] = fexp(sc0 - m);
        if (has2) sE[wid][64 + lane] = fexp(sc1 - m);

        const float emi0 = en0, emi1 = en1;
        const unsigned int mki = mk_n;
        if (i + 1 < SS) {                   // prefetch next step
            rp += TT;
            en0 = rp[t0];
            en1 = rp[t1c];
            mk_n = mask_int ? mi32[b * SS + i + 1] : (unsigned int)mi8[b * SS + i + 1];
        }
        __builtin_amdgcn_wave_barrier();    // keep reads after writes (no HW cost)

        // ---- load the ENTIRE exp-state vector into registers first ----
        // (forces all 20 ds_read_b128 into flight back-to-back; LDS latency
        //  paid once ~360cyc instead of 20x serialized ~1200cyc)
        const v4f* ep = (const v4f*)sE[wid];
        v4f xs[TP / 4];
        #pragma unroll
        for (int k = 0; k < TP / 4; ++k) xs[k] = ep[k];

        // matvec: v[t] = sum_j E[j] * exp(trans[j][t]); packed fp32 FMAs
        v2f a0 = {0.f, 0.f}, a1 = {0.f, 0.f};   // accumulators for t0
        v2f c0 = {0.f, 0.f}, c1 = {0.f, 0.f};   // accumulators for t1
        #pragma unroll
        for (int k = 0; k < TP / 4; ++k) {      // 20 iters, 4 pk-FMA each
            v2f xlo = {xs[k].x, xs[k].y};
            v2f xhi = {xs[k].z, xs[k].w};
            a0 = __builtin_elementwise_fma(xlo, et0[2 * k + 0], a0);
            a1 = __builtin_elementwise_fma(xhi, et0[2 * k + 1], a1);
            c0 = __builtin_elementwise_fma(xlo, et1[2 * k + 0], c0);
            c1 = __builtin_elementwise_fma(xhi, et1[2 * k + 1], c1);
        }
        v2f va = a0 + a1;
        v2f vc = c0 + c1;
        float v0 = va.x + va.y;
        float v1 = vc.x + vc.y;

        float nsc0 = emi0 + m + flog(v0);
        float nsc1 = emi1 + m + flog(v1);
        const bool upd = is_alpha | (mki != 0);   // alpha always updates
        sc0 = upd ? nsc0 : sc0;
        sc1 = upd ? nsc1 : sc1;
    }

    // ---- final: lse over tags with end transitions (in-wave reduce) ----
    float f0 = sc0 + en_[t0];
    float f1 = has2 ? (sc1 + en_[t1c]) : -1e30f;
    float mm = fmaxf(f0, f1);
    #pragma unroll
    for (int o = 32; o > 0; o >>= 1) mm = fmaxf(mm, __shfl_xor(mm, o));
    float s = fexp(f0 - mm) + (has2 ? fexp(f1 - mm) : 0.f);
    #pragma unroll
    for (int o = 32; o > 0; o >>= 1) s += __shfl_xor(s, o);
    if (lane == 0) sfin[wid] = mm + flog(s);
    __syncthreads();
    if (tid == 0) out[b] = sfin[1] - sfin[0];   // partition - score_final
}

extern "C" void kernel_launch(void* const* d_in, const int* in_sizes, int n_in,
                              void* d_out, int out_size, void* d_ws, size_t ws_size,
                              hipStream_t stream) {
    const float* emissions    = (const float*)d_in[0];
    const unsigned int* mask  = (const unsigned int*)d_in[1];
    const float* start_trans  = (const float*)d_in[2];
    const float* end_trans    = (const float*)d_in[3];
    const float* transitions  = (const float*)d_in[4];
    float* out = (float*)d_out;

    crf_fwd_kernel<<<BB, NT, 0, stream>>>(emissions, mask, start_trans,
                                          end_trans, transitions, out);
}